// Round 1
// baseline (1922.190 us; speedup 1.0000x reference)
//
#include <hip/hip_runtime.h>

#define B_ 4096
#define S_ 64
#define H_ 512
#define BM 128
#define BN 64
#define BK 64
#define NIT (H_ / BK) // 8

typedef _Float16 half8 __attribute__((ext_vector_type(8)));
typedef _Float16 half4 __attribute__((ext_vector_type(4)));
typedef float float4v __attribute__((ext_vector_type(4)));
typedef unsigned int uint4v __attribute__((ext_vector_type(4)));

// ---------------- weight fp32 -> fp16 conversion (once per launch) ----------------
__global__ void convert_weights_kernel(const float* __restrict__ Wr, const float* __restrict__ W,
                                       const float* __restrict__ Ur, const float* __restrict__ U,
                                       _Float16* __restrict__ out) {
    const float* src;
    switch (blockIdx.y) {
        case 0: src = Wr; break;
        case 1: src = W;  break;
        case 2: src = Ur; break;
        default: src = U; break;
    }
    int i = (blockIdx.x * blockDim.x + threadIdx.x) * 8;
    float4v a = *(const float4v*)(src + i);
    float4v b = *(const float4v*)(src + i + 4);
    half8 h;
    h[0] = (_Float16)a[0]; h[1] = (_Float16)a[1]; h[2] = (_Float16)a[2]; h[3] = (_Float16)a[3];
    h[4] = (_Float16)b[0]; h[5] = (_Float16)b[1]; h[6] = (_Float16)b[2]; h[7] = (_Float16)b[3];
    *(half8*)(out + (size_t)blockIdx.y * H_ * H_ + i) = h;
}

// ---------------- fused recurrent step ----------------
// Computes, for all (b, o) in its tile:
//   a    = facts_t@Wr^T + C@Ur^T + br + bur ; r = sigmoid(a)
//   htil = tanh(facts_t@W^T + bw + r*(C@U^T + bu))
//   Cnew = g*htil + (1-g)*C
// Weights layout in wf: [Wr, W, Ur, U][o][h] fp16. acc index w matches.
template<bool LAST>
__global__ __launch_bounds__(256, 1)
void gru_step_kernel(const float* __restrict__ facts, const float* __restrict__ G,
                     const _Float16* __restrict__ wf,
                     const float* __restrict__ br, const float* __restrict__ bur,
                     const float* __restrict__ bw, const float* __restrict__ bu,
                     const _Float16* __restrict__ c_in, _Float16* __restrict__ c_out,
                     float* __restrict__ out32, int t)
{
    extern __shared__ _Float16 sm[]; // 2 x (facts 128x64 | C 128x64 | W 4x64x64) halves = 131072 B
    const int tid = threadIdx.x;
    const int lane = tid & 63;
    const int wid = tid >> 6;      // 4 waves
    const int l15 = lane & 15;
    const int l4  = lane >> 4;
    const int wm = wid >> 1;       // wave row group (0..1), 64 rows each
    const int wn = wid & 1;        // wave col group (0..1), 32 cols each
    const int b0 = blockIdx.x * BM;
    const int n0 = blockIdx.y * BN;

    float4v acc[4][4][2];
#pragma unroll
    for (int w = 0; w < 4; ++w)
#pragma unroll
        for (int m = 0; m < 4; ++m)
#pragma unroll
            for (int n = 0; n < 2; ++n)
                acc[w][m][n] = (float4v){0.f, 0.f, 0.f, 0.f};

    // staging registers (next tile, in flight during compute)
    float4v sf[8];   // facts fp32, 4 floats each
    uint4v  scv[4];  // C halves, 16B each
    uint4v  swv[8];  // weight halves, 16B each

    const int f_row = wid * 32 + l4;           // + j*4  (facts rows per wave: 32)
    const int f_col = l15 * 4;                 // float offset within BK
    const int c_row = wid * 32 + (lane >> 3);  // + j*8
    const int c_chk = lane & 7;                // 16B chunk within BK
    const int w_row = lane >> 3;               // + j*8  (wave wid stages matrix wid)

    const float* fbase = facts + ((size_t)b0 * S_ + t) * H_;

    auto issue = [&](int kk) {
        const int k0 = kk * BK;
#pragma unroll
        for (int j = 0; j < 8; ++j)
            sf[j] = *(const float4v*)(fbase + (size_t)(f_row + j * 4) * (S_ * H_) + k0 + f_col);
#pragma unroll
        for (int j = 0; j < 4; ++j)
            scv[j] = *(const uint4v*)(c_in + (size_t)(b0 + c_row + j * 8) * H_ + k0 + c_chk * 8);
#pragma unroll
        for (int j = 0; j < 8; ++j)
            swv[j] = *(const uint4v*)(wf + (size_t)wid * (H_ * H_) + (size_t)(n0 + w_row + j * 8) * H_ + k0 + c_chk * 8);
    };

    // XOR-swizzled (16B-chunk granularity) unpadded LDS layout: conflict-free reads+writes
    auto stage = [&](int sel) {
        _Float16* bf  = sm + sel * 32768;
        _Float16* bc  = bf + 8192;
        _Float16* bwt = bf + 16384;
#pragma unroll
        for (int j = 0; j < 8; ++j) {
            int row = f_row + j * 4;
            half4 h;
            h[0] = (_Float16)sf[j][0]; h[1] = (_Float16)sf[j][1];
            h[2] = (_Float16)sf[j][2]; h[3] = (_Float16)sf[j][3];
            int c16 = (l15 >> 1) ^ (row & 7);
            *(half4*)&bf[row * 64 + c16 * 8 + (l15 & 1) * 4] = h;
        }
#pragma unroll
        for (int j = 0; j < 4; ++j) {
            int row = c_row + j * 8;
            *(uint4v*)&bc[row * 64 + ((c_chk ^ (row & 7)) << 3)] = scv[j];
        }
#pragma unroll
        for (int j = 0; j < 8; ++j) {
            int row = w_row + j * 8;
            *(uint4v*)&bwt[(wid * 64 + row) * 64 + ((c_chk ^ (row & 7)) << 3)] = swv[j];
        }
    };

    auto compute = [&](int sel) {
        const _Float16* bf  = sm + sel * 32768;
        const _Float16* bc  = bf + 8192;
        const _Float16* bwt = bf + 16384;
#pragma unroll
        for (int s = 0; s < 2; ++s) {
            half8 fa[4], fc[4], wb[4][2];
            const int kc = s * 4 + l4;
#pragma unroll
            for (int m = 0; m < 4; ++m) {
                int row = wm * 64 + m * 16 + l15;
                int off = row * 64 + ((kc ^ (row & 7)) << 3);
                fa[m] = *(const half8*)&bf[off];
                fc[m] = *(const half8*)&bc[off];
            }
#pragma unroll
            for (int w = 0; w < 4; ++w)
#pragma unroll
                for (int n = 0; n < 2; ++n) {
                    int row = wn * 32 + n * 16 + l15;
                    wb[w][n] = *(const half8*)&bwt[(w * 64 + row) * 64 + ((kc ^ (row & 7)) << 3)];
                }
#pragma unroll
            for (int m = 0; m < 4; ++m)
#pragma unroll
                for (int n = 0; n < 2; ++n) {
                    acc[0][m][n] = __builtin_amdgcn_mfma_f32_16x16x32_f16(fa[m], wb[0][n], acc[0][m][n], 0, 0, 0);
                    acc[1][m][n] = __builtin_amdgcn_mfma_f32_16x16x32_f16(fa[m], wb[1][n], acc[1][m][n], 0, 0, 0);
                    acc[2][m][n] = __builtin_amdgcn_mfma_f32_16x16x32_f16(fc[m], wb[2][n], acc[2][m][n], 0, 0, 0);
                    acc[3][m][n] = __builtin_amdgcn_mfma_f32_16x16x32_f16(fc[m], wb[3][n], acc[3][m][n], 0, 0, 0);
                }
        }
    };

    issue(0);
#pragma unroll
    for (int kk = 0; kk < NIT; ++kk) {
        stage(kk & 1);               // waits (vmcnt) on staged regs automatically
        if (kk + 1 < NIT) issue(kk + 1); // next tile in flight during barrier+compute
        __syncthreads();             // one barrier per iter (double-buffered LDS)
        compute(kk & 1);
    }

    // ---------------- epilogue ----------------
    const int col_base = n0 + wn * 32;
    const int row_base = b0 + wm * 64;
#pragma unroll
    for (int n = 0; n < 2; ++n) {
        const int col = col_base + n * 16 + l15;
        const float brv = br[col] + bur[col];
        const float bwv = bw[col];
        const float buv = bu[col];
#pragma unroll
        for (int m = 0; m < 4; ++m) {
#pragma unroll
            for (int r = 0; r < 4; ++r) {
                const int row = row_base + m * 16 + l4 * 4 + r;
                float apre = acc[0][m][n][r] + acc[2][m][n][r] + brv;
                float rg = 1.0f / (1.0f + __expf(-apre));
                float x = (acc[1][m][n][r] + bwv) + rg * (acc[3][m][n][r] + buv);
                float e2 = __expf(2.0f * x);
                float ht = 1.0f - 2.0f / (e2 + 1.0f);   // tanh(x), saturates correctly at +-inf
                float g = G[(size_t)row * S_ + t];
                float cold = (float)c_in[(size_t)row * H_ + col];
                float h = g * ht + (1.0f - g) * cold;
                if (LAST) out32[(size_t)row * H_ + col] = h;
                else      c_out[(size_t)row * H_ + col] = (_Float16)h;
            }
        }
    }
}

extern "C" void kernel_launch(void* const* d_in, const int* in_sizes, int n_in,
                              void* d_out, int out_size, void* d_ws, size_t ws_size,
                              hipStream_t stream) {
    const float* facts = (const float*)d_in[0];
    const float* G     = (const float*)d_in[1];
    const float* Wr    = (const float*)d_in[2];
    const float* br    = (const float*)d_in[3];
    const float* Ur    = (const float*)d_in[4];
    const float* bur   = (const float*)d_in[5];
    const float* W     = (const float*)d_in[6];
    const float* bw    = (const float*)d_in[7];
    const float* U     = (const float*)d_in[8];
    const float* bu    = (const float*)d_in[9];

    _Float16* wf16 = (_Float16*)d_ws;                 // 4*512*512 fp16 = 2 MB
    _Float16* c0   = wf16 + 4 * H_ * H_;              // 4096*512 fp16 = 4 MB
    _Float16* c1   = c0 + (size_t)B_ * H_;            // 4 MB

    hipMemsetAsync(c0, 0, (size_t)B_ * H_ * sizeof(_Float16), stream); // C0 = 0
    convert_weights_kernel<<<dim3(H_ * H_ / (256 * 8), 4), 256, 0, stream>>>(Wr, W, Ur, U, wf16);

    dim3 grid(B_ / BM, H_ / BN); // 32 x 8 = 256 blocks
    const size_t lds = 131072;   // 128 KiB
    _Float16* bufs[2] = {c0, c1};
    for (int t = 0; t < S_; ++t) {
        _Float16* cin  = bufs[t & 1];
        _Float16* cout = bufs[(t & 1) ^ 1];
        if (t == S_ - 1)
            gru_step_kernel<true><<<grid, 256, lds, stream>>>(facts, G, wf16, br, bur, bw, bu,
                                                              cin, cout, (float*)d_out, t);
        else
            gru_step_kernel<false><<<grid, 256, lds, stream>>>(facts, G, wf16, br, bur, bw, bu,
                                                               cin, cout, nullptr, t);
    }
}